// Round 3
// baseline (109.822 us; speedup 1.0000x reference)
//
#include <hip/hip_runtime.h>
#include <math.h>

#define BLOCK 256
#define NRPT 4          // rays per thread -> float4-aligned I/O, 2 packed pairs
#define HIDDEN_ 128
#define MAXIT 64

typedef float v2f __attribute__((ext_vector_type(2)));

__device__ __forceinline__ v2f ld2(const float* p) {
    return *reinterpret_cast<const v2f*>(p);
}

// Packed fp32 helpers. Weights live in SGPR pairs ("s" constraint, uniform
// s_load); individual weight scalars are broadcast into both halves via
// VOP3P op_sel/op_sel_hi half-selection (H=0 -> lo, H=1 -> hi). Each pk op
// reads exactly one scalar operand (the 64b sgpr pair) -> legal.
template<int H>
__device__ __forceinline__ v2f pk_mul_b(v2f a, v2f b) {
    v2f d;
    if constexpr (H == 0)
        asm("v_pk_mul_f32 %0, %1, %2 op_sel:[0,0] op_sel_hi:[1,0]"
            : "=v"(d) : "v"(a), "s"(b));
    else
        asm("v_pk_mul_f32 %0, %1, %2 op_sel:[0,1] op_sel_hi:[1,1]"
            : "=v"(d) : "v"(a), "s"(b));
    return d;
}
template<int H>
__device__ __forceinline__ v2f pk_fma_b(v2f a, v2f b, v2f c) {
    v2f d;
    if constexpr (H == 0)
        asm("v_pk_fma_f32 %0, %1, %2, %3 op_sel:[0,0,0] op_sel_hi:[1,0,1]"
            : "=v"(d) : "v"(a), "s"(b), "v"(c));
    else
        asm("v_pk_fma_f32 %0, %1, %2, %3 op_sel:[0,1,0] op_sel_hi:[1,1,1]"
            : "=v"(d) : "v"(a), "s"(b), "v"(c));
    return d;
}
template<int H>
__device__ __forceinline__ v2f pk_add_b(v2f a, v2f b) {
    v2f d;
    if constexpr (H == 0)
        asm("v_pk_add_f32 %0, %1, %2 op_sel:[0,0] op_sel_hi:[1,0]"
            : "=v"(d) : "v"(a), "s"(b));
    else
        asm("v_pk_add_f32 %0, %1, %2 op_sel:[0,1] op_sel_hi:[1,1]"
            : "=v"(d) : "v"(a), "s"(b));
    return d;
}
// NOTE: gfx950 has NO v_pk_max_f32 (packed fp32 is fma/mul/add only).
// ReLU as two scalar v_max_f32.
__device__ __forceinline__ v2f pk_relu(v2f a) {
    v2f d;
    d.x = fmaxf(a.x, 0.0f);
    d.y = fmaxf(a.y, 0.0f);
    return d;
}

__global__ __launch_bounds__(BLOCK) void sphere_trace_kernel(
    const float* __restrict__ origins,
    const float* __restrict__ directions,
    const float* __restrict__ center,
    const float* __restrict__ radius,
    const float* __restrict__ W1,
    const float* __restrict__ b1,
    const float* __restrict__ W2,
    const float* __restrict__ b2,
    float* __restrict__ out,
    int nray)
{
    const float cx = center[0], cy = center[1], cz = center[2];
    const float rad = radius[0];
    const float bo0 = b2[0], bo1 = b2[1], bo2 = b2[2];

    const int tid = threadIdx.x;
    const int base = (blockIdx.x * BLOCK + tid) * NRPT;
    if (base >= nray) return;

    const float4* o4 = reinterpret_cast<const float4*>(origins + 3 * (size_t)base);
    const float4* d4 = reinterpret_cast<const float4*>(directions + 3 * (size_t)base);
    const float4 oA = o4[0], oB = o4[1], oC = o4[2];
    const float4 dA = d4[0], dB = d4[1], dC = d4[2];

    float qx[NRPT], qy[NRPT], qz[NRPT];   // q = p - center
    float dx[NRPT], dy[NRPT], dz[NRPT];

    qx[0] = oA.x - cx; qy[0] = oA.y - cy; qz[0] = oA.z - cz;
    qx[1] = oA.w - cx; qy[1] = oB.x - cy; qz[1] = oB.y - cz;
    qx[2] = oB.z - cx; qy[2] = oB.w - cy; qz[2] = oC.x - cz;
    qx[3] = oC.y - cx; qy[3] = oC.z - cy; qz[3] = oC.w - cz;

    dx[0] = dA.x; dy[0] = dA.y; dz[0] = dA.z;
    dx[1] = dA.w; dy[1] = dB.x; dz[1] = dB.y;
    dx[2] = dB.z; dy[2] = dB.w; dz[2] = dC.x;
    dx[3] = dC.y; dy[3] = dC.z; dz[3] = dC.w;

    float slast[NRPT], sprev[NRPT];
#pragma unroll
    for (int r = 0; r < NRPT; ++r) { slast[r] = 0.0f; sprev[r] = INFINITY; }

    // Sphere tracing. Mask = (sdf of last executed iter) < 1e-4.
    // Early-exit vote every 4 iters, wave-uniform:
    //  converged: s < 1e-5  (monotone decreasing for hit rays -> mask stays
    //             true; residual motion <= 64e-5 -> negligible color delta)
    //  dead:      s >= s(4 iters ago) && s > 1e-3. A hitting ray's sdf is
    //             strictly decreasing (first hit precedes closest approach),
    //             so growth proves a miss; sdf is then monotone increasing,
    //             so the reference's iter-64 sdf >= s > 1e-3 > eps -> mask
    //             false on both sides. Exact mask equivalence.
    for (int ob = 0; ob < MAXIT / 4; ++ob) {
#pragma unroll
        for (int ii = 0; ii < 4; ++ii) {
#pragma unroll
            for (int r = 0; r < NRPT; ++r) {
                float f = qx[r] * qx[r];
                f = fmaf(qy[r], qy[r], f);
                f = fmaf(qz[r], qz[r], f);
                const float s = __builtin_amdgcn_sqrtf(f) - rad;
                qx[r] = fmaf(s, dx[r], qx[r]);
                qy[r] = fmaf(s, dy[r], qy[r]);
                qz[r] = fmaf(s, dz[r], qz[r]);
                slast[r] = s;
            }
        }
        bool done = true;
#pragma unroll
        for (int r = 0; r < NRPT; ++r) {
            const float s = slast[r];
            const bool conv = s < 1e-5f;
            const bool dead = (s >= sprev[r]) && (s > 1e-3f);
            done = done && (conv || dead || !(s == s));
            sprev[r] = s;
        }
        if (__all(done)) break;
    }

    // Fused MLP, packed fp32: rays paired (0,1) and (2,3) into v2f.
    // Weights stay in SGPRs (uniform s_load), broadcast via op_sel.
    v2f pxp[2], pyp[2], pzp[2];
    pxp[0] = v2f{qx[0] + cx, qx[1] + cx};
    pyp[0] = v2f{qy[0] + cy, qy[1] + cy};
    pzp[0] = v2f{qz[0] + cz, qz[1] + cz};
    pxp[1] = v2f{qx[2] + cx, qx[3] + cx};
    pyp[1] = v2f{qy[2] + cy, qy[3] + cy};
    pzp[1] = v2f{qz[2] + cz, qz[3] + cz};

    v2f a0p[2], a1p[2], a2p[2];
    a0p[0] = v2f{bo0, bo0}; a1p[0] = v2f{bo1, bo1}; a2p[0] = v2f{bo2, bo2};
    a0p[1] = a0p[0];        a1p[1] = a1p[0];        a2p[1] = a2p[0];

    // Two hidden units per step: weight pairs are adjacent in memory.
    // W1 is [3][128] (row k at offset 128k); W2 is [128][3]:
    //   Ap={W2[j][0],W2[j][1]} Bp={W2[j][2],W2[j+1][0]} Cp={W2[j+1][1],W2[j+1][2]}
#pragma unroll 4
    for (int j = 0; j < HIDDEN_; j += 2) {
        const v2f w0p = ld2(W1 + j);
        const v2f w1p = ld2(W1 + HIDDEN_ + j);
        const v2f w2p = ld2(W1 + 2 * HIDDEN_ + j);
        const v2f bbp = ld2(b1 + j);
        const v2f Ap  = ld2(W2 + 3 * j);
        const v2f Bp  = ld2(W2 + 3 * j + 2);
        const v2f Cp  = ld2(W2 + 3 * j + 4);
#pragma unroll
        for (int pr = 0; pr < 2; ++pr) {
            v2f t0 = pk_mul_b<0>(pxp[pr], w0p);
            t0 = pk_fma_b<0>(pyp[pr], w1p, t0);
            t0 = pk_fma_b<0>(pzp[pr], w2p, t0);
            const v2f hj = pk_relu(pk_add_b<0>(t0, bbp));

            v2f t1 = pk_mul_b<1>(pxp[pr], w0p);
            t1 = pk_fma_b<1>(pyp[pr], w1p, t1);
            t1 = pk_fma_b<1>(pzp[pr], w2p, t1);
            const v2f hj1 = pk_relu(pk_add_b<1>(t1, bbp));

            a0p[pr] = pk_fma_b<0>(hj, Ap, a0p[pr]);   // W2[j][0]
            a1p[pr] = pk_fma_b<1>(hj, Ap, a1p[pr]);   // W2[j][1]
            a2p[pr] = pk_fma_b<0>(hj, Bp, a2p[pr]);   // W2[j][2]
            a0p[pr] = pk_fma_b<1>(hj1, Bp, a0p[pr]);  // W2[j+1][0]
            a1p[pr] = pk_fma_b<0>(hj1, Cp, a1p[pr]);  // W2[j+1][1]
            a2p[pr] = pk_fma_b<1>(hj1, Cp, a2p[pr]);  // W2[j+1][2]
        }
    }

    float a0[NRPT], a1[NRPT], a2[NRPT];
    a0[0] = a0p[0].x; a0[1] = a0p[0].y; a0[2] = a0p[1].x; a0[3] = a0p[1].y;
    a1[0] = a1p[0].x; a1[1] = a1p[0].y; a1[2] = a1p[1].x; a1[3] = a1p[1].y;
    a2[0] = a2p[0].x; a2[1] = a2p[0].y; a2[2] = a2p[1].x; a2[3] = a2p[1].y;

    float colv[NRPT][3];
#pragma unroll
    for (int r = 0; r < NRPT; ++r) {
        const bool hit = slast[r] < 0.0001f;   // SDF_EPS
        const float c0 = __builtin_amdgcn_rcpf(1.0f + __expf(-a0[r]));
        const float c1 = __builtin_amdgcn_rcpf(1.0f + __expf(-a1[r]));
        const float c2 = __builtin_amdgcn_rcpf(1.0f + __expf(-a2[r]));
        colv[r][0] = hit ? c0 : 0.0f;   // select, not multiply: kills NaN/inf
        colv[r][1] = hit ? c1 : 0.0f;
        colv[r][2] = hit ? c2 : 0.0f;
    }

    float4* ov = reinterpret_cast<float4*>(out + 3 * (size_t)base);
    ov[0] = make_float4(colv[0][0], colv[0][1], colv[0][2], colv[1][0]);
    ov[1] = make_float4(colv[1][1], colv[1][2], colv[2][0], colv[2][1]);
    ov[2] = make_float4(colv[2][2], colv[3][0], colv[3][1], colv[3][2]);
}

extern "C" void kernel_launch(void* const* d_in, const int* in_sizes, int n_in,
                              void* d_out, int out_size, void* d_ws, size_t ws_size,
                              hipStream_t stream) {
    (void)d_ws; (void)ws_size; (void)n_in; (void)out_size;
    const float* origins    = (const float*)d_in[0];
    const float* directions = (const float*)d_in[1];
    const float* center     = (const float*)d_in[2];
    const float* radius     = (const float*)d_in[3];
    const float* W1         = (const float*)d_in[4];
    const float* b1         = (const float*)d_in[5];
    const float* W2         = (const float*)d_in[6];
    const float* b2         = (const float*)d_in[7];
    float* out = (float*)d_out;

    const int nray = in_sizes[0] / 3;
    const int blocks = (nray + BLOCK * NRPT - 1) / (BLOCK * NRPT);
    sphere_trace_kernel<<<blocks, BLOCK, 0, stream>>>(
        origins, directions, center, radius, W1, b1, W2, b2, out, nray);
}

// Round 4
// 108.980 us; speedup vs baseline: 1.0077x; 1.0077x over previous
//
#include <hip/hip_runtime.h>
#include <math.h>

#define BLOCK 256
#define NRPT 4          // rays per thread -> float4-aligned I/O, 2 packed pairs
#define HIDDEN_ 128
#define MAXIT 64

typedef float v2f __attribute__((ext_vector_type(2)));

__device__ __forceinline__ v2f ld2(const float* p) {
    return *reinterpret_cast<const v2f*>(p);
}

// Packed fp32 helpers (gfx950 VOP3P: v_pk_fma/mul/add_f32 only; NO v_pk_max).
// Weights live in SGPR pairs ("s"); op_sel broadcasts one half (H=0 lo, H=1 hi).
template<int H>
__device__ __forceinline__ v2f pk_mul_b(v2f a, v2f b) {
    v2f d;
    if constexpr (H == 0)
        asm("v_pk_mul_f32 %0, %1, %2 op_sel:[0,0] op_sel_hi:[1,0]"
            : "=v"(d) : "v"(a), "s"(b));
    else
        asm("v_pk_mul_f32 %0, %1, %2 op_sel:[0,1] op_sel_hi:[1,1]"
            : "=v"(d) : "v"(a), "s"(b));
    return d;
}
template<int H>
__device__ __forceinline__ v2f pk_fma_b(v2f a, v2f b, v2f c) {
    v2f d;
    if constexpr (H == 0)
        asm("v_pk_fma_f32 %0, %1, %2, %3 op_sel:[0,0,0] op_sel_hi:[1,0,1]"
            : "=v"(d) : "v"(a), "s"(b), "v"(c));
    else
        asm("v_pk_fma_f32 %0, %1, %2, %3 op_sel:[0,1,0] op_sel_hi:[1,1,1]"
            : "=v"(d) : "v"(a), "s"(b), "v"(c));
    return d;
}
template<int H>
__device__ __forceinline__ v2f pk_add_b(v2f a, v2f b) {
    v2f d;
    if constexpr (H == 0)
        asm("v_pk_add_f32 %0, %1, %2 op_sel:[0,0] op_sel_hi:[1,0]"
            : "=v"(d) : "v"(a), "s"(b));
    else
        asm("v_pk_add_f32 %0, %1, %2 op_sel:[0,1] op_sel_hi:[1,1]"
            : "=v"(d) : "v"(a), "s"(b));
    return d;
}
__device__ __forceinline__ v2f pk_relu(v2f a) {
    v2f d;
    d.x = fmaxf(a.x, 0.0f);
    d.y = fmaxf(a.y, 0.0f);
    return d;
}

__global__ __launch_bounds__(BLOCK) void sphere_trace_kernel(
    const float* __restrict__ origins,
    const float* __restrict__ directions,
    const float* __restrict__ center,
    const float* __restrict__ radius,
    const float* __restrict__ W1,
    const float* __restrict__ b1,
    const float* __restrict__ W2,
    const float* __restrict__ b2,
    float* __restrict__ out,
    int nray)
{
    const float cx = center[0], cy = center[1], cz = center[2];
    const float rad = radius[0];
    const float bo0 = b2[0], bo1 = b2[1], bo2 = b2[2];

    const int tid = threadIdx.x;
    const int base = (blockIdx.x * BLOCK + tid) * NRPT;
    if (base >= nray) return;

    const float4* o4 = reinterpret_cast<const float4*>(origins + 3 * (size_t)base);
    const float4* d4 = reinterpret_cast<const float4*>(directions + 3 * (size_t)base);
    const float4 oA = o4[0], oB = o4[1], oC = o4[2];
    const float4 dA = d4[0], dB = d4[1], dC = d4[2];

    float qx[NRPT], qy[NRPT], qz[NRPT];   // q = p - center
    float dx[NRPT], dy[NRPT], dz[NRPT];

    qx[0] = oA.x - cx; qy[0] = oA.y - cy; qz[0] = oA.z - cz;
    qx[1] = oA.w - cx; qy[1] = oB.x - cy; qz[1] = oB.y - cz;
    qx[2] = oB.z - cx; qy[2] = oB.w - cy; qz[2] = oC.x - cz;
    qx[3] = oC.y - cx; qy[3] = oC.z - cy; qz[3] = oC.w - cz;

    dx[0] = dA.x; dy[0] = dA.y; dz[0] = dA.z;
    dx[1] = dA.w; dy[1] = dB.x; dz[1] = dB.y;
    dx[2] = dB.z; dy[2] = dB.w; dz[2] = dC.x;
    dx[3] = dC.y; dy[3] = dC.z; dz[3] = dC.w;

    // ---- Analytic classification (exact-sphere sphere tracing) ----
    // f(t)=sqrt(b^2+(t-tc)^2)-r is convex => eps_{n+1} <= (1-mu) eps_n with
    // mu = sqrt(disc)/r evaluated at the hit. So:
    //  fasthit  (tc>0, disc >= 0.0625 r^2, start well outside): mu>=0.25 =>
    //           ref s_63 <= t* * 0.75^63 < 5e-8 < EPS  -> mask TRUE, and the
    //           64-iter point == analytic intersection to <1e-7.
    //  fastmiss (disc < -2.5e-3 r^2): sdf >= b-r > 1e-3 everywhere -> mask
    //           FALSE guaranteed. Also tc<=0 while well outside: f
    //           non-decreasing for t>=0, sdf_63 >= sdf_0 > EPS -> FALSE.
    //  slow     (thin band: grazing hits / near-tangent misses / near-inside
    //           starts): run the exact 64-iter reference loop, predicated.
    float slast[NRPT];
    bool  slow[NRPT];
    const float r2 = rad * rad;
    const float thr_hit  = 0.0625f * r2;     // mu >= 0.25
    const float thr_miss = -2.5e-3f * r2;    // b - r > ~1.25e-3
    const float rout = (rad + 0.05f) * (rad + 0.05f);
    bool anySlow = false;
#pragma unroll
    for (int r = 0; r < NRPT; ++r) {
        float nq2 = qx[r] * qx[r];
        nq2 = fmaf(qy[r], qy[r], nq2);
        nq2 = fmaf(qz[r], qz[r], nq2);
        float tc = -(qx[r] * dx[r]);
        tc = fmaf(-qy[r], dy[r], tc);
        tc = fmaf(-qz[r], dz[r], tc);
        const float disc = fmaf(tc, tc, r2 - nq2);   // r^2 - (|q|^2 - tc^2)
        const bool outside = nq2 > rout;
        const bool fasthit = outside && (tc > 0.0f) && (disc >= thr_hit);
        const bool fastmiss = outside && ((disc < thr_miss) || (tc <= 0.0f));
        slow[r] = !(fasthit || fastmiss);
        anySlow = anySlow || slow[r];
        if (fasthit) {
            const float tstar = tc - __builtin_amdgcn_sqrtf(disc);
            qx[r] = fmaf(tstar, dx[r], qx[r]);
            qy[r] = fmaf(tstar, dy[r], qy[r]);
            qz[r] = fmaf(tstar, dz[r], qz[r]);
        }
        slast[r] = fasthit ? 0.0f : 1.0f;   // hit: 0<EPS; miss: 1>EPS
    }

    // ---- Slow path: exact reference loop (predicated per ray), wave-skipped.
    if (__any(anySlow)) {
        float sprev[NRPT];
#pragma unroll
        for (int r = 0; r < NRPT; ++r) sprev[r] = INFINITY;
        for (int ob = 0; ob < MAXIT / 4; ++ob) {
#pragma unroll
            for (int ii = 0; ii < 4; ++ii) {
#pragma unroll
                for (int r = 0; r < NRPT; ++r) {
                    float f = qx[r] * qx[r];
                    f = fmaf(qy[r], qy[r], f);
                    f = fmaf(qz[r], qz[r], f);
                    const float s = __builtin_amdgcn_sqrtf(f) - rad;
                    const float nx = fmaf(s, dx[r], qx[r]);
                    const float ny = fmaf(s, dy[r], qy[r]);
                    const float nz = fmaf(s, dz[r], qz[r]);
                    qx[r] = slow[r] ? nx : qx[r];
                    qy[r] = slow[r] ? ny : qy[r];
                    qz[r] = slow[r] ? nz : qz[r];
                    slast[r] = slow[r] ? s : slast[r];
                }
            }
            bool done = true;
#pragma unroll
            for (int r = 0; r < NRPT; ++r) {
                const float s = slast[r];
                const bool conv = s < 1e-5f;
                const bool dead = (s >= sprev[r]) && (s > 1e-3f);
                done = done && (!slow[r] || conv || dead || !(s == s));
                sprev[r] = s;
            }
            if (__all(done)) break;
        }
    }

    // ---- Fused MLP, packed fp32: rays paired (0,1) and (2,3) into v2f.
    v2f pxp[2], pyp[2], pzp[2];
    pxp[0] = v2f{qx[0] + cx, qx[1] + cx};
    pyp[0] = v2f{qy[0] + cy, qy[1] + cy};
    pzp[0] = v2f{qz[0] + cz, qz[1] + cz};
    pxp[1] = v2f{qx[2] + cx, qx[3] + cx};
    pyp[1] = v2f{qy[2] + cy, qy[3] + cy};
    pzp[1] = v2f{qz[2] + cz, qz[3] + cz};

    v2f a0p[2], a1p[2], a2p[2];
    a0p[0] = v2f{bo0, bo0}; a1p[0] = v2f{bo1, bo1}; a2p[0] = v2f{bo2, bo2};
    a0p[1] = a0p[0];        a1p[1] = a1p[0];        a2p[1] = a2p[0];

    // W1 is [3][128]; W2 is [128][3]:
    //   Ap={W2[j][0],W2[j][1]} Bp={W2[j][2],W2[j+1][0]} Cp={W2[j+1][1],W2[j+1][2]}
#pragma unroll 4
    for (int j = 0; j < HIDDEN_; j += 2) {
        const v2f w0p = ld2(W1 + j);
        const v2f w1p = ld2(W1 + HIDDEN_ + j);
        const v2f w2p = ld2(W1 + 2 * HIDDEN_ + j);
        const v2f bbp = ld2(b1 + j);
        const v2f Ap  = ld2(W2 + 3 * j);
        const v2f Bp  = ld2(W2 + 3 * j + 2);
        const v2f Cp  = ld2(W2 + 3 * j + 4);
#pragma unroll
        for (int pr = 0; pr < 2; ++pr) {
            v2f t0 = pk_mul_b<0>(pxp[pr], w0p);
            t0 = pk_fma_b<0>(pyp[pr], w1p, t0);
            t0 = pk_fma_b<0>(pzp[pr], w2p, t0);
            const v2f hj = pk_relu(pk_add_b<0>(t0, bbp));

            v2f t1 = pk_mul_b<1>(pxp[pr], w0p);
            t1 = pk_fma_b<1>(pyp[pr], w1p, t1);
            t1 = pk_fma_b<1>(pzp[pr], w2p, t1);
            const v2f hj1 = pk_relu(pk_add_b<1>(t1, bbp));

            a0p[pr] = pk_fma_b<0>(hj, Ap, a0p[pr]);   // W2[j][0]
            a1p[pr] = pk_fma_b<1>(hj, Ap, a1p[pr]);   // W2[j][1]
            a2p[pr] = pk_fma_b<0>(hj, Bp, a2p[pr]);   // W2[j][2]
            a0p[pr] = pk_fma_b<1>(hj1, Bp, a0p[pr]);  // W2[j+1][0]
            a1p[pr] = pk_fma_b<0>(hj1, Cp, a1p[pr]);  // W2[j+1][1]
            a2p[pr] = pk_fma_b<1>(hj1, Cp, a2p[pr]);  // W2[j+1][2]
        }
    }

    float a0[NRPT], a1[NRPT], a2[NRPT];
    a0[0] = a0p[0].x; a0[1] = a0p[0].y; a0[2] = a0p[1].x; a0[3] = a0p[1].y;
    a1[0] = a1p[0].x; a1[1] = a1p[0].y; a1[2] = a1p[1].x; a1[3] = a1p[1].y;
    a2[0] = a2p[0].x; a2[1] = a2p[0].y; a2[2] = a2p[1].x; a2[3] = a2p[1].y;

    float colv[NRPT][3];
#pragma unroll
    for (int r = 0; r < NRPT; ++r) {
        const bool hit = slast[r] < 0.0001f;   // SDF_EPS
        const float c0 = __builtin_amdgcn_rcpf(1.0f + __expf(-a0[r]));
        const float c1 = __builtin_amdgcn_rcpf(1.0f + __expf(-a1[r]));
        const float c2 = __builtin_amdgcn_rcpf(1.0f + __expf(-a2[r]));
        colv[r][0] = hit ? c0 : 0.0f;   // select, not multiply: kills NaN/inf
        colv[r][1] = hit ? c1 : 0.0f;
        colv[r][2] = hit ? c2 : 0.0f;
    }

    float4* ov = reinterpret_cast<float4*>(out + 3 * (size_t)base);
    ov[0] = make_float4(colv[0][0], colv[0][1], colv[0][2], colv[1][0]);
    ov[1] = make_float4(colv[1][1], colv[1][2], colv[2][0], colv[2][1]);
    ov[2] = make_float4(colv[2][2], colv[3][0], colv[3][1], colv[3][2]);
}

extern "C" void kernel_launch(void* const* d_in, const int* in_sizes, int n_in,
                              void* d_out, int out_size, void* d_ws, size_t ws_size,
                              hipStream_t stream) {
    (void)d_ws; (void)ws_size; (void)n_in; (void)out_size;
    const float* origins    = (const float*)d_in[0];
    const float* directions = (const float*)d_in[1];
    const float* center     = (const float*)d_in[2];
    const float* radius     = (const float*)d_in[3];
    const float* W1         = (const float*)d_in[4];
    const float* b1         = (const float*)d_in[5];
    const float* W2         = (const float*)d_in[6];
    const float* b2         = (const float*)d_in[7];
    float* out = (float*)d_out;

    const int nray = in_sizes[0] / 3;
    const int blocks = (nray + BLOCK * NRPT - 1) / (BLOCK * NRPT);
    sphere_trace_kernel<<<blocks, BLOCK, 0, stream>>>(
        origins, directions, center, radius, W1, b1, W2, b2, out, nray);
}